// Round 4
// baseline (18244.237 us; speedup 1.0000x reference)
//
#include <hip/hip_runtime.h>
#include <cmath>

// ESN forward scan on MI355X — round 4.
// Round-3 accounting: compute ~0.5 us/step (VALUBusy 12.4%), modeled sync
// ~0.8 us, observed 4.0 us -> ~2.5 us unexplained wait. Suspects: exchange
// transaction pressure (16 dwordx4 poll instrs/CU/round; 16 scattered 4-B
// partial-line publish stores/block = RMW at coherence point) and the
// publish store queued BEHIND the out store's HBM write-allocate RFO.
// Round-4 changes:
//   1. 1-bit tag stolen from fp16 bit14 (|h| < 1 always, so bit14==0 in
//      every payload; ping-pong buffers mean tag only needs to distinguish
//      step t from t-2 -> (t>>1)&1 suffices). Exchange = 2 B/row, 8 KB:
//      poll = 2 dwordx4/thread (was 4), publish = ONE 8-B dwordx2 per wave
//      (was 4x 4-B partial stores).
//   2. Publish BEFORE the out store (out's RFO no longer delays visibility).
//   3. __syncthreads() after hreg loads: closes the latent intra-block race
//      (a wave's poll slice does NOT cover sibling waves' blocks, so the
//      round-3 "poll gates hl overwrite" argument was unsound).
// Unchanged: 256 blocks x 256 thr, Wh as fp16 in 128 VGPRs/thread, fp32
// leak chain, v_dot2 accumulation, butterfly reduce, cooperative launch.

#define T_STEPS  4096
#define R_SIZE   4096
#define I_SIZE   3
#define OUT_COLS (R_SIZE + I_SIZE)   // 4099
#define NB       256                 // blocks == CUs; all co-resident
#define BT       256                 // threads per block (4 waves)
#define RPB      16                  // rows per block
#define RPW      4                   // rows per wave
#define LEAK     0.1f
#define TAG_MASK 0x40004000u         // bit14 of each fp16 half

typedef _Float16 h2 __attribute__((ext_vector_type(2)));
typedef _Float16 h8 __attribute__((ext_vector_type(8)));
typedef unsigned u32x2 __attribute__((ext_vector_type(2)));
typedef unsigned u32x4 __attribute__((ext_vector_type(4)));

__device__ __forceinline__ float fdot2f(h2 a, h2 b, float c) {
#if __has_builtin(__builtin_amdgcn_fdot2)
    return __builtin_amdgcn_fdot2(a, b, c, false);
#else
    return c + (float)a[0] * (float)b[0] + (float)a[1] * (float)b[1];
#endif
}

// 8 dwords (16 rows) in flight with L1/L2 bypass, one waitcnt.
__device__ __forceinline__ void poll8(const unsigned* p, u32x4& a0, u32x4& a1) {
    asm volatile(
        "global_load_dwordx4 %0, %2, off sc0 sc1\n\t"
        "global_load_dwordx4 %1, %2, off offset:16 sc0 sc1\n\t"
        "s_waitcnt vmcnt(0)"
        : "=&v"(a0), "=&v"(a1)
        : "v"(p)
        : "memory");
}

__global__ void __launch_bounds__(BT, 1) esn_kernel(
    const float* __restrict__ Wh,   // [R, R] row-major fp32
    const float* __restrict__ Win,  // [R, 3]
    const float* __restrict__ x,    // [T, 3]
    float* __restrict__ out,        // [T, 4099]
    unsigned* __restrict__ ex0,     // exchange buf A: 2048 dwords (2 B/row)
    unsigned* __restrict__ ex1)     // exchange buf B: 2048 dwords
{
    __shared__ alignas(16) _Float16 hl[R_SIZE];   // 8 KB

    const int tid  = threadIdx.x;
    const int bid  = blockIdx.x;
    const int wv   = tid >> 6;
    const int lane = tid & 63;
    const int r0   = bid * RPB;

    // ---- one-time: this wave's 4 Wh rows -> fp16 registers ----
    h8 wreg[RPW * 8];
    #pragma unroll
    for (int rr = 0; rr < RPW; ++rr) {
        const float* src = Wh + (size_t)(r0 + wv * RPW + rr) * R_SIZE;
        #pragma unroll
        for (int j = 0; j < 8; ++j) {
            int e = (j * 64 + lane) * 8;
            float4 a = *(const float4*)(src + e);
            float4 b = *(const float4*)(src + e + 4);
            h8 hv;
            hv[0] = (_Float16)a.x; hv[1] = (_Float16)a.y;
            hv[2] = (_Float16)a.z; hv[3] = (_Float16)a.w;
            hv[4] = (_Float16)b.x; hv[5] = (_Float16)b.y;
            hv[6] = (_Float16)b.z; hv[7] = (_Float16)b.w;
            wreg[rr * 8 + j] = hv;
        }
    }

    // publisher lanes (lane<4) cache their row's Win
    float win0 = 0.f, win1 = 0.f, win2 = 0.f;
    if (lane < RPW) {
        int r = r0 + wv * RPW + lane;
        win0 = Win[(size_t)r * I_SIZE + 0];
        win1 = Win[(size_t)r * I_SIZE + 1];
        win2 = Win[(size_t)r * I_SIZE + 2];
    }
    float hown = 0.0f;   // fp32 leak chain, h0 = 0

    // thread tid polls rows [tid*16, tid*16+16) = dwords [tid*8, tid*8+8)
    const unsigned* pr[2] = { ex0 + tid * 8, ex1 + tid * 8 };

    for (int t = 0; t < T_STEPS; ++t) {
        const int par = t & 1;
        unsigned* __restrict__ exw = par ? ex0 : ex1;       // buffer (t+1)&1
        const unsigned tagexp  = ((unsigned)t >> 1) & 1u;   // expected this step
        const unsigned tagbit  = (((unsigned)t + 1u) >> 1) & 1u;  // published

        const float xt0 = x[t * 3 + 0];
        const float xt1 = x[t * 3 + 1];
        const float xt2 = x[t * 3 + 2];

        // ---- batched poll: 8 dwords (16 rows), every fp16 bit14 == tagexp ----
        u32x4 a0, a1;
        for (;;) {
            poll8(pr[par], a0, a1);
            unsigned andv = a0[0] & a0[1] & a0[2] & a0[3]
                          & a1[0] & a1[1] & a1[2] & a1[3];
            unsigned orv  = a0[0] | a0[1] | a0[2] | a0[3]
                          | a1[0] | a1[1] | a1[2] | a1[3];
            bool ok = tagexp ? ((andv & TAG_MASK) == TAG_MASK)
                             : ((orv  & TAG_MASK) == 0u);
            if (ok) break;
            __builtin_amdgcn_s_sleep(1);
        }

        // ---- strip tags, stage 32 B to LDS ----
        {
            u32x4 s0, s1;
            #pragma unroll
            for (int i = 0; i < 4; ++i) { s0[i] = a0[i] & ~TAG_MASK;
                                          s1[i] = a1[i] & ~TAG_MASK; }
            u32x4* hl4 = (u32x4*)hl;
            hl4[tid * 2 + 0] = s0;
            hl4[tid * 2 + 1] = s1;
        }
        __syncthreads();

        // ---- per-lane h chunk into registers ----
        h8 hreg[8];
        const h8* hl8 = (const h8*)hl;
        #pragma unroll
        for (int j = 0; j < 8; ++j) hreg[j] = hl8[j * 64 + lane];
        __syncthreads();   // safety: no wave may overwrite hl (next step)
                           // until all waves have read it

        // ---- 4 rows per wave: register weights, dot2-accumulate ----
        float acc[RPW];
        #pragma unroll
        for (int rr = 0; rr < RPW; ++rr) {
            float a = 0.0f;
            #pragma unroll
            for (int j = 0; j < 8; ++j) {
                h8 w8 = wreg[rr * 8 + j];
                h8 hh = hreg[j];
                a = fdot2f(__builtin_shufflevector(w8, w8, 0, 1),
                           __builtin_shufflevector(hh, hh, 0, 1), a);
                a = fdot2f(__builtin_shufflevector(w8, w8, 2, 3),
                           __builtin_shufflevector(hh, hh, 2, 3), a);
                a = fdot2f(__builtin_shufflevector(w8, w8, 4, 5),
                           __builtin_shufflevector(hh, hh, 4, 5), a);
                a = fdot2f(__builtin_shufflevector(w8, w8, 6, 7),
                           __builtin_shufflevector(hh, hh, 6, 7), a);
            }
            #pragma unroll
            for (int s = 32; s; s >>= 1) a += __shfl_xor(a, s, 64);
            acc[rr] = a;
        }

        // ---- epilogue: finish rows, publish FIRST, then write out ----
        float hv = 0.0f;
        unsigned hw = 0;
        if (lane < RPW) {
            float a = (lane == 0) ? acc[0]
                    : (lane == 1) ? acc[1]
                    : (lane == 2) ? acc[2] : acc[3];
            float u  = xt0 * win0 + xt1 * win1 + xt2 * win2;
            float hn = tanhf(u + a);
            hv = LEAK * hown + (1.0f - LEAK) * hn;   // |hv| < 1 by induction
            hown = hv;
            unsigned short hb = __builtin_bit_cast(unsigned short, (_Float16)hv);
            hw = (unsigned)hb | (tagbit << 14);
        }
        // pack the wave's 4 rows into one 8-B word (lanes 0..3 valid)
        unsigned s0 = __shfl(hw, 0), s1 = __shfl(hw, 1);
        unsigned s2 = __shfl(hw, 2), s3 = __shfl(hw, 3);
        if (lane == 0) {
            u32x2 w; w[0] = s0 | (s1 << 16); w[1] = s2 | (s3 << 16);
            unsigned* dst = exw + (unsigned)(bid * 8 + wv * 2);
            asm volatile("global_store_dwordx2 %0, %1, off sc0 sc1"
                         :: "v"(dst), "v"(w) : "memory");
        }
        if (lane < RPW) {
            out[(size_t)t * OUT_COLS + r0 + wv * RPW + lane] = hv;
        }
    }
}

__global__ void init_kernel(unsigned* __restrict__ ex0,
                            unsigned* __restrict__ ex1) {
    int i = blockIdx.x * blockDim.x + threadIdx.x;
    if (i < R_SIZE / 2) {
        ex0[i] = 0u;            // tag 0, h = 0  -> valid initial state, step 0
        ex1[i] = TAG_MASK;      // tag 1 != expected tag 0 at step 1 -> wait
    }
}

__global__ void copy_x_kernel(const float* __restrict__ x, float* __restrict__ out) {
    int i = blockIdx.x * blockDim.x + threadIdx.x;
    if (i < T_STEPS * I_SIZE) {
        int t = i / I_SIZE, c = i % I_SIZE;
        out[(size_t)t * OUT_COLS + R_SIZE + c] = x[i];
    }
}

extern "C" void kernel_launch(void* const* d_in, const int* in_sizes, int n_in,
                              void* d_out, int out_size, void* d_ws, size_t ws_size,
                              hipStream_t stream) {
    // setup_inputs order: x [T,3], Win [R,3], Wh [R,R]; all fp32.
    const float* x   = (const float*)d_in[0];
    const float* Win = (const float*)d_in[1];
    const float* Wh  = (const float*)d_in[2];
    float* out = (float*)d_out;

    // ws layout: two exchange buffers of R/2 dwords (8 KB) each.
    unsigned* ex0 = (unsigned*)d_ws;
    unsigned* ex1 = ex0 + R_SIZE / 2;

    init_kernel<<<dim3((R_SIZE / 2 + BT - 1) / BT), dim3(BT), 0, stream>>>(ex0, ex1);
    copy_x_kernel<<<dim3((T_STEPS * I_SIZE + BT - 1) / BT), dim3(BT), 0, stream>>>(x, out);

    void* args[] = {(void*)&Wh, (void*)&Win, (void*)&x, (void*)&out,
                    (void*)&ex0, (void*)&ex1};
    hipError_t e = hipLaunchCooperativeKernel((void*)esn_kernel, dim3(NB), dim3(BT),
                                              args, 0, stream);
    if (e != hipSuccess) {
        // Fallback: plain launch; 256 blocks x 4 waves always co-resident.
        esn_kernel<<<dim3(NB), dim3(BT), 0, stream>>>(Wh, Win, x, out, ex0, ex1);
    }
}